// Round 2
// baseline (1131.378 us; speedup 1.0000x reference)
//
#include <hip/hip_runtime.h>
#include <hip/hip_bf16.h>

#define T_SEQ 1024

__device__ __forceinline__ float fast_sigmoid(float x) {
    return 1.0f / (1.0f + __expf(-x));
}
__device__ __forceinline__ float fast_tanh(float x) {
    float e = __expf(2.0f * x);
    return 1.0f - 2.0f / (e + 1.0f);
}

// K1: precompute u-dependent parts of both RNN linears (+bias)
__global__ __launch_bounds__(256) void k_rnn_pre(
    const float* __restrict__ u,
    const float* __restrict__ i2h_w, const float* __restrict__ i2h_b,
    const float* __restrict__ h2o_w, const float* __restrict__ h2o_b,
    float* __restrict__ pre_i, float* __restrict__ pre_o) {
    int idx = blockIdx.x * 256 + threadIdx.x;   // 0..65535
    int k = idx >> 6, i = idx & 63;
    float a = i2h_b[i], b = h2o_b[i];
#pragma unroll
    for (int c = 0; c < 8; ++c) {
        float uv = u[k * 8 + c];
        a += uv * i2h_w[i * 72 + c];
        b += uv * h2o_w[i * 72 + c];
    }
    pre_i[idx] = a;
    pre_o[idx] = b;
}

// K2: serial h-chain, ONE wave, no barriers. Lane i owns h_i and weight row
// w[i][0..63] in 64 VGPRs. Broadcast h_j via v_readlane (immediate lane idx).
__global__ __launch_bounds__(64) void k_rnn_chain(
    const float* __restrict__ i2h_w,
    const float* __restrict__ pre_i,
    float* __restrict__ hseq) {
    int i = threadIdx.x;
    float w[64];
#pragma unroll
    for (int j = 0; j < 64; ++j) w[j] = i2h_w[i * 72 + 8 + j];
    float h = 0.0f;
    float pre = pre_i[i];                       // pre for k=0
    for (int k = 0; k < T_SEQ; ++k) {
        hseq[k * 64 + i] = h;                   // carry BEFORE step k
        float pre_next = (k + 1 < T_SEQ) ? pre_i[(k + 1) * 64 + i] : 0.0f;
        int hb = __float_as_int(h);
        float a0 = pre, a1 = 0.0f, a2 = 0.0f, a3 = 0.0f;
#pragma unroll
        for (int j = 0; j < 64; j += 4) {
            a0 += w[j + 0] * __int_as_float(__builtin_amdgcn_readlane(hb, j + 0));
            a1 += w[j + 1] * __int_as_float(__builtin_amdgcn_readlane(hb, j + 1));
            a2 += w[j + 2] * __int_as_float(__builtin_amdgcn_readlane(hb, j + 2));
            a3 += w[j + 3] * __int_as_float(__builtin_amdgcn_readlane(hb, j + 3));
        }
        h = fast_tanh((a0 + a1) + (a2 + a3));
        pre = pre_next;
    }
}

// K3: all RNN outputs in parallel
__global__ __launch_bounds__(64) void k_rnn_out(
    const float* __restrict__ h2o_w,
    const float* __restrict__ pre_o,
    const float* __restrict__ hseq,
    float* __restrict__ uout) {
    int k = blockIdx.x, i = threadIdx.x;
    __shared__ float hk[64];
    hk[i] = hseq[k * 64 + i];
    __syncthreads();
    float acc = pre_o[k * 64 + i];
#pragma unroll
    for (int m = 0; m < 64; ++m) acc += h2o_w[i * 72 + 8 + m] * hk[m];
    uout[k * 64 + i] = fast_tanh(acc);
}

// ---- K4: fused batch kernel, 2 rows/thread ----
// LDS float offsets. w1 rows stored as [w(t)] at +0, [w(x0..x63)] at +4..+67
// (16B-aligned float4 region). cwT rows stride 68 (aligned), transposed.
#define L_XW1 0       // 20*68
#define L_XB1 1360    // 20
#define L_XW2 1380    // 400
#define L_XB2 1780    // 20
#define L_XW3 1800    // 1280
#define L_XB3 3080    // 64
#define L_UW1 3144    // 20*68
#define L_UB1 4504    // 20
#define L_UW2 4524    // 400
#define L_UB2 4924    // 20
#define L_UW3 4944    // 1280
#define L_UB3 6224    // 64
#define L_CWT 6288    // 128*68  (cwT[j][s] = cw[s*128+j])
#define L_CB  14992   // 64
#define L_TOT 15056   // 60224 bytes -> 2 blocks/CU

template <int OW1, int OB1, int OW2, int OB2>
__device__ __forceinline__ void mlp2(const float* __restrict__ sm,
                                     float tA, float tB,
                                     const float4* zA, const float4* zB,
                                     float* h2A, float* h2B) {
    float h1A[20], h1B[20];
#pragma unroll
    for (int o = 0; o < 20; ++o) {
        const int ro = OW1 + o * 68;
        float w0 = sm[ro];
        float aA = sm[OB1 + o] + tA * w0;
        float aB = sm[OB1 + o] + tB * w0;
        const float4* wr = reinterpret_cast<const float4*>(&sm[ro + 4]);
#pragma unroll
        for (int v = 0; v < 16; ++v) {
            float4 w4 = wr[v];
            aA += zA[v].x * w4.x + zA[v].y * w4.y + zA[v].z * w4.z + zA[v].w * w4.w;
            aB += zB[v].x * w4.x + zB[v].y * w4.y + zB[v].z * w4.z + zB[v].w * w4.w;
        }
        h1A[o] = fast_sigmoid(aA);
        h1B[o] = fast_sigmoid(aB);
    }
#pragma unroll
    for (int o = 0; o < 20; ++o) {
        float aA = sm[OB2 + o], aB = aA;
        const float4* wr = reinterpret_cast<const float4*>(&sm[OW2 + o * 20]);
#pragma unroll
        for (int v = 0; v < 5; ++v) {
            float4 w4 = wr[v];
            aA += h1A[4*v+0]*w4.x + h1A[4*v+1]*w4.y + h1A[4*v+2]*w4.z + h1A[4*v+3]*w4.w;
            aB += h1B[4*v+0]*w4.x + h1B[4*v+1]*w4.y + h1B[4*v+2]*w4.z + h1B[4*v+3]*w4.w;
        }
        h2A[o] = fast_sigmoid(aA);
        h2B[o] = fast_sigmoid(aB);
    }
}

template <int OW3, int OB3, int OCWT>
__device__ __forceinline__ void final64(const float* __restrict__ sm,
                                        const float* h2A, const float* h2B,
                                        float* oA, float* oB) {
#pragma unroll 2
    for (int o = 0; o < 64; ++o) {
        float aA = sm[OB3 + o], aB = aA;
        const float4* wr = reinterpret_cast<const float4*>(&sm[OW3 + o * 20]);
#pragma unroll
        for (int v = 0; v < 5; ++v) {
            float4 w4 = wr[v];
            aA += h2A[4*v+0]*w4.x + h2A[4*v+1]*w4.y + h2A[4*v+2]*w4.z + h2A[4*v+3]*w4.w;
            aB += h2B[4*v+0]*w4.x + h2B[4*v+1]*w4.y + h2B[4*v+2]*w4.z + h2B[4*v+3]*w4.w;
        }
        float sA = fast_sigmoid(aA), sB = fast_sigmoid(aB);
        const float4* cr = reinterpret_cast<const float4*>(&sm[OCWT + o * 68]);
#pragma unroll
        for (int v = 0; v < 16; ++v) {
            float4 c4 = cr[v];
            oA[4*v+0] += sA * c4.x; oA[4*v+1] += sA * c4.y;
            oA[4*v+2] += sA * c4.z; oA[4*v+3] += sA * c4.w;
            oB[4*v+0] += sB * c4.x; oB[4*v+1] += sB * c4.y;
            oB[4*v+2] += sB * c4.z; oB[4*v+3] += sB * c4.w;
        }
    }
}

__global__ __launch_bounds__(256, 2) void k_batch(
    const float* __restrict__ t_in, const float* __restrict__ x_in,
    const float* __restrict__ uout,
    const float* __restrict__ xw1, const float* __restrict__ xb1,
    const float* __restrict__ xw2, const float* __restrict__ xb2,
    const float* __restrict__ xw3, const float* __restrict__ xb3,
    const float* __restrict__ uw1, const float* __restrict__ ub1,
    const float* __restrict__ uw2, const float* __restrict__ ub2,
    const float* __restrict__ uw3, const float* __restrict__ ub3,
    const float* __restrict__ cw, const float* __restrict__ cb,
    float* __restrict__ out) {
    __shared__ float sm[L_TOT];
    const int tid = threadIdx.x;
    for (int idx = tid; idx < 1300; idx += 256) {
        int o = idx / 65, j = idx - o * 65;
        int dst = (j == 0) ? o * 68 : o * 68 + 3 + j;
        sm[L_XW1 + dst] = xw1[idx];
        sm[L_UW1 + dst] = uw1[idx];
    }
    for (int idx = tid; idx < 400; idx += 256) {
        sm[L_XW2 + idx] = xw2[idx];
        sm[L_UW2 + idx] = uw2[idx];
    }
    for (int idx = tid; idx < 1280; idx += 256) {
        sm[L_XW3 + idx] = xw3[idx];
        sm[L_UW3 + idx] = uw3[idx];
    }
    if (tid < 20) {
        sm[L_XB1 + tid] = xb1[tid]; sm[L_XB2 + tid] = xb2[tid];
        sm[L_UB1 + tid] = ub1[tid]; sm[L_UB2 + tid] = ub2[tid];
    }
    if (tid < 64) {
        sm[L_XB3 + tid] = xb3[tid]; sm[L_UB3 + tid] = ub3[tid];
        sm[L_CB + tid] = cb[tid];
    }
    // conflict-free transpose: lanes walk s (contiguous LDS), j uniform-ish
    for (int idx = tid; idx < 8192; idx += 256) {
        int j = idx >> 6, s = idx & 63;
        sm[L_CWT + j * 68 + s] = cw[s * 128 + j];
    }
    __syncthreads();

    const int r0 = blockIdx.x * 512 + tid;
    const int r1 = r0 + 256;
    float tA = t_in[r0], tB = t_in[r1];
    float4 zA[16], zB[16];
    const float4* xpA = reinterpret_cast<const float4*>(x_in + (size_t)r0 * 64);
    const float4* xpB = reinterpret_cast<const float4*>(x_in + (size_t)r1 * 64);
#pragma unroll
    for (int v = 0; v < 16; ++v) { zA[v] = xpA[v]; zB[v] = xpB[v]; }

    float h2sA[20], h2sB[20];
    mlp2<L_XW1, L_XB1, L_XW2, L_XB2>(sm, tA, tB, zA, zB, h2sA, h2sB);

    int tiA = min((int)(tA * 1024.0f), 1023);
    int tiB = min((int)(tB * 1024.0f), 1023);
    const float4* epA = reinterpret_cast<const float4*>(uout + tiA * 64);
    const float4* epB = reinterpret_cast<const float4*>(uout + tiB * 64);
#pragma unroll
    for (int v = 0; v < 16; ++v) { zA[v] = epA[v]; zB[v] = epB[v]; }

    float h2cA[20], h2cB[20];
    mlp2<L_UW1, L_UB1, L_UW2, L_UB2>(sm, tA, tB, zA, zB, h2cA, h2cB);

    float oA[64], oB[64];
#pragma unroll
    for (int s = 0; s < 64; ++s) { oA[s] = sm[L_CB + s]; oB[s] = oA[s]; }
    final64<L_XW3, L_XB3, L_CWT>(sm, h2sA, h2sB, oA, oB);
    final64<L_UW3, L_UB3, L_CWT + 64 * 68>(sm, h2cA, h2cB, oA, oB);

    float4* opA = reinterpret_cast<float4*>(out + (size_t)r0 * 64);
    float4* opB = reinterpret_cast<float4*>(out + (size_t)r1 * 64);
#pragma unroll
    for (int v = 0; v < 16; ++v) {
        float4 fA, fB;
        fA.x = oA[4*v+0]; fA.y = oA[4*v+1]; fA.z = oA[4*v+2]; fA.w = oA[4*v+3];
        fB.x = oB[4*v+0]; fB.y = oB[4*v+1]; fB.z = oB[4*v+2]; fB.w = oB[4*v+3];
        opA[v] = fA;
        opB[v] = fB;
    }
}

extern "C" void kernel_launch(void* const* d_in, const int* in_sizes, int n_in,
                              void* d_out, int out_size, void* d_ws, size_t ws_size,
                              hipStream_t stream) {
    const float* t     = (const float*)d_in[0];
    const float* x     = (const float*)d_in[1];
    const float* u     = (const float*)d_in[2];
    const float* i2h_w = (const float*)d_in[3];
    const float* i2h_b = (const float*)d_in[4];
    const float* h2o_w = (const float*)d_in[5];
    const float* h2o_b = (const float*)d_in[6];
    const float* xw1 = (const float*)d_in[7];  const float* xb1 = (const float*)d_in[8];
    const float* xw2 = (const float*)d_in[9];  const float* xb2 = (const float*)d_in[10];
    const float* xw3 = (const float*)d_in[11]; const float* xb3 = (const float*)d_in[12];
    const float* uw1 = (const float*)d_in[13]; const float* ub1 = (const float*)d_in[14];
    const float* uw2 = (const float*)d_in[15]; const float* ub2 = (const float*)d_in[16];
    const float* uw3 = (const float*)d_in[17]; const float* ub3 = (const float*)d_in[18];
    const float* cw  = (const float*)d_in[19]; const float* cb  = (const float*)d_in[20];
    float* out = (float*)d_out;

    float* ws    = (float*)d_ws;
    float* pre_i = ws;                 // 65536 floats
    float* pre_o = ws + 65536;
    float* hseq  = ws + 131072;
    float* uo    = ws + 196608;

    int Bv = in_sizes[0];              // 262144

    hipLaunchKernelGGL(k_rnn_pre, dim3(256), dim3(256), 0, stream,
                       u, i2h_w, i2h_b, h2o_w, h2o_b, pre_i, pre_o);
    hipLaunchKernelGGL(k_rnn_chain, dim3(1), dim3(64), 0, stream,
                       i2h_w, pre_i, hseq);
    hipLaunchKernelGGL(k_rnn_out, dim3(T_SEQ), dim3(64), 0, stream,
                       h2o_w, pre_o, hseq, uo);
    hipLaunchKernelGGL(k_batch, dim3(Bv / 512), dim3(256), 0, stream,
                       t, x, uo,
                       xw1, xb1, xw2, xb2, xw3, xb3,
                       uw1, ub1, uw2, ub2, uw3, ub3,
                       cw, cb, out);
}

// Round 3
// 855.721 us; speedup vs baseline: 1.3221x; 1.3221x over previous
//
#include <hip/hip_runtime.h>
#include <hip/hip_bf16.h>

#define T_SEQ 1024

__device__ __forceinline__ float fast_sigmoid(float x) {
    return 1.0f / (1.0f + __expf(-x));
}
__device__ __forceinline__ float fast_tanh(float x) {
    float e = __expf(2.0f * x);
    return 1.0f - 2.0f / (e + 1.0f);
}

// K1: precompute u-dependent parts of both RNN linears (+bias)
__global__ __launch_bounds__(256) void k_rnn_pre(
    const float* __restrict__ u,
    const float* __restrict__ i2h_w, const float* __restrict__ i2h_b,
    const float* __restrict__ h2o_w, const float* __restrict__ h2o_b,
    float* __restrict__ pre_i, float* __restrict__ pre_o) {
    int idx = blockIdx.x * 256 + threadIdx.x;   // 0..65535
    int k = idx >> 6, i = idx & 63;
    float a = i2h_b[i], b = h2o_b[i];
#pragma unroll
    for (int c = 0; c < 8; ++c) {
        float uv = u[k * 8 + c];
        a += uv * i2h_w[i * 72 + c];
        b += uv * h2o_w[i * 72 + c];
    }
    pre_i[idx] = a;
    pre_o[idx] = b;
}

// K2: the sequential h-chain. 1 block, 256 threads = 4 waves.
// Wave q computes partial sums over m in [16q,16q+16). hseq[k] = h BEFORE step k.
// (round-1 version: measured best so far; the readlane variant regressed)
__global__ __launch_bounds__(256) void k_rnn_chain(
    const float* __restrict__ i2h_w,
    const float* __restrict__ pre_i,
    float* __restrict__ hseq) {
    __shared__ float h[64];
    __shared__ float part[4][64];
    int t = threadIdx.x, i = t & 63, q = t >> 6;
    float w[16];
#pragma unroll
    for (int j = 0; j < 16; ++j) w[j] = i2h_w[i * 72 + 8 + 16 * q + j];
    if (q == 0) h[i] = 0.0f;
    float pre_next = (q == 0) ? pre_i[i] : 0.0f;   // pre for k=0
    __syncthreads();
    for (int k = 0; k < T_SEQ; ++k) {
        float pre_cur = pre_next;
        if (q == 0) {
            hseq[k * 64 + i] = h[i];               // carry at step k
            if (k + 1 < T_SEQ) pre_next = pre_i[(k + 1) * 64 + i];  // prefetch
        }
        float acc = 0.0f;
#pragma unroll
        for (int j = 0; j < 16; ++j) acc += w[j] * h[16 * q + j];
        part[q][i] = acc;
        __syncthreads();
        if (q == 0) {
            float s = part[0][i] + part[1][i] + part[2][i] + part[3][i] + pre_cur;
            h[i] = fast_tanh(s);
        }
        __syncthreads();
    }
}

// K3: all RNN outputs in parallel
__global__ __launch_bounds__(64) void k_rnn_out(
    const float* __restrict__ h2o_w,
    const float* __restrict__ pre_o,
    const float* __restrict__ hseq,
    float* __restrict__ uout) {
    int k = blockIdx.x, i = threadIdx.x;
    __shared__ float hk[64];
    hk[i] = hseq[k * 64 + i];
    __syncthreads();
    float acc = pre_o[k * 64 + i];
#pragma unroll
    for (int m = 0; m < 64; ++m) acc += h2o_w[i * 72 + 8 + m] * hk[m];
    uout[k * 64 + i] = fast_tanh(acc);
}

// K-repack: pad/transpose weights into 16B-aligned, wave-uniform-readable rows.
// Layout in wp (floats):
//   [0,1360)      xw1p rows of 68: {w_t, pad, pad, pad, w_x0..w_x63}
//   [1360,2720)   uw1p same
//   [2720,3120)   xw2 copy   [3120,3520) uw2 copy      (rows of 20 = 80B, aligned)
//   [3520,4800)   xw3 copy   [4800,6080) uw3 copy
//   [6080,14272)  cwT[128][64]: cwT[j][s] = cw[s*128+j]
__global__ __launch_bounds__(256) void k_repack(
    const float* __restrict__ xw1, const float* __restrict__ uw1,
    const float* __restrict__ xw2, const float* __restrict__ uw2,
    const float* __restrict__ xw3, const float* __restrict__ uw3,
    const float* __restrict__ cw, float* __restrict__ wp) {
    int i = blockIdx.x * 256 + threadIdx.x;
    if (i < 1360) {
        int o = i / 68, c = i - o * 68;
        float xv = 0.0f, uv = 0.0f;
        if (c == 0)      { xv = xw1[o * 65];         uv = uw1[o * 65]; }
        else if (c >= 4) { xv = xw1[o * 65 + c - 3]; uv = uw1[o * 65 + c - 3]; }
        wp[i] = xv; wp[1360 + i] = uv;
    } else if (i < 1760) {
        int j = i - 1360; wp[2720 + j] = xw2[j]; wp[3120 + j] = uw2[j];
    } else if (i < 3040) {
        int j = i - 1760; wp[3520 + j] = xw3[j]; wp[4800 + j] = uw3[j];
    } else if (i < 11232) {
        int j = i - 3040; int row = j >> 6, s = j & 63;
        wp[6080 + j] = cw[s * 128 + row];
    }
}

// ---- K4: fused batch kernel, 1 row/thread, NO LDS ----
// All weight reads are wave-uniform, 16B-aligned -> scalar (s_load) path.
__device__ __forceinline__ void mlp20(const float* __restrict__ w1,
                                      const float* __restrict__ b1,
                                      const float* __restrict__ w2,
                                      const float* __restrict__ b2,
                                      float tval, const float4* z, float* h2) {
    float h1[20];
#pragma unroll
    for (int o = 0; o < 20; ++o) {
        float a = b1[o] + tval * w1[o * 68];
        const float4* wr = reinterpret_cast<const float4*>(w1 + o * 68 + 4);
#pragma unroll
        for (int v = 0; v < 16; ++v) {
            float4 w4 = wr[v];
            a += z[v].x * w4.x + z[v].y * w4.y + z[v].z * w4.z + z[v].w * w4.w;
        }
        h1[o] = fast_sigmoid(a);
    }
#pragma unroll
    for (int o = 0; o < 20; ++o) {
        float a = b2[o];
        const float4* wr = reinterpret_cast<const float4*>(w2 + o * 20);
#pragma unroll
        for (int v = 0; v < 5; ++v) {
            float4 w4 = wr[v];
            a += h1[4*v+0]*w4.x + h1[4*v+1]*w4.y + h1[4*v+2]*w4.z + h1[4*v+3]*w4.w;
        }
        h2[o] = fast_sigmoid(a);
    }
}

__device__ __forceinline__ void final64(const float* __restrict__ w3,
                                        const float* __restrict__ b3,
                                        const float* __restrict__ cwt,
                                        const float* h2, float* oacc) {
#pragma unroll 4
    for (int o = 0; o < 64; ++o) {
        float a = b3[o];
        const float4* wr = reinterpret_cast<const float4*>(w3 + o * 20);
#pragma unroll
        for (int v = 0; v < 5; ++v) {
            float4 w4 = wr[v];
            a += h2[4*v+0]*w4.x + h2[4*v+1]*w4.y + h2[4*v+2]*w4.z + h2[4*v+3]*w4.w;
        }
        float s = fast_sigmoid(a);
        const float4* cr = reinterpret_cast<const float4*>(cwt + o * 64);
#pragma unroll
        for (int v = 0; v < 16; ++v) {
            float4 c4 = cr[v];
            oacc[4*v+0] += s * c4.x; oacc[4*v+1] += s * c4.y;
            oacc[4*v+2] += s * c4.z; oacc[4*v+3] += s * c4.w;
        }
    }
}

__global__ __launch_bounds__(256) void k_batch(
    const float* __restrict__ t_in, const float* __restrict__ x_in,
    const float* __restrict__ uo, const float* __restrict__ wp,
    const float* __restrict__ xb1, const float* __restrict__ xb2,
    const float* __restrict__ xb3,
    const float* __restrict__ ub1, const float* __restrict__ ub2,
    const float* __restrict__ ub3,
    const float* __restrict__ cb, float* __restrict__ out) {
    const int r = blockIdx.x * 256 + threadIdx.x;
    float tval = t_in[r];
    float4 z[16];
    const float4* xp = reinterpret_cast<const float4*>(x_in + (size_t)r * 64);
#pragma unroll
    for (int v = 0; v < 16; ++v) z[v] = xp[v];

    float h2s[20], h2c[20];
    mlp20(wp + 0, xb1, wp + 2720, xb2, tval, z, h2s);

    int ti = min((int)(tval * 1024.0f), 1023);
    const float4* ep = reinterpret_cast<const float4*>(uo + ti * 64);
#pragma unroll
    for (int v = 0; v < 16; ++v) z[v] = ep[v];
    mlp20(wp + 1360, ub1, wp + 3120, ub2, tval, z, h2c);

    float oacc[64];
#pragma unroll
    for (int s = 0; s < 64; ++s) oacc[s] = cb[s];
    final64(wp + 3520, xb3, wp + 6080, h2s, oacc);
    final64(wp + 4800, ub3, wp + 6080 + 4096, h2c, oacc);

    float4* op = reinterpret_cast<float4*>(out + (size_t)r * 64);
#pragma unroll
    for (int v = 0; v < 16; ++v) {
        float4 f;
        f.x = oacc[4*v+0]; f.y = oacc[4*v+1];
        f.z = oacc[4*v+2]; f.w = oacc[4*v+3];
        op[v] = f;
    }
}

extern "C" void kernel_launch(void* const* d_in, const int* in_sizes, int n_in,
                              void* d_out, int out_size, void* d_ws, size_t ws_size,
                              hipStream_t stream) {
    const float* t     = (const float*)d_in[0];
    const float* x     = (const float*)d_in[1];
    const float* u     = (const float*)d_in[2];
    const float* i2h_w = (const float*)d_in[3];
    const float* i2h_b = (const float*)d_in[4];
    const float* h2o_w = (const float*)d_in[5];
    const float* h2o_b = (const float*)d_in[6];
    const float* xw1 = (const float*)d_in[7];  const float* xb1 = (const float*)d_in[8];
    const float* xw2 = (const float*)d_in[9];  const float* xb2 = (const float*)d_in[10];
    const float* xw3 = (const float*)d_in[11]; const float* xb3 = (const float*)d_in[12];
    const float* uw1 = (const float*)d_in[13]; const float* ub1 = (const float*)d_in[14];
    const float* uw2 = (const float*)d_in[15]; const float* ub2 = (const float*)d_in[16];
    const float* uw3 = (const float*)d_in[17]; const float* ub3 = (const float*)d_in[18];
    const float* cw  = (const float*)d_in[19]; const float* cb  = (const float*)d_in[20];
    float* out = (float*)d_out;

    float* ws    = (float*)d_ws;
    float* pre_i = ws;                 // [0,65536)        dead after chain
    float* pre_o = ws + 65536;         // [65536,131072)   dead after k_rnn_out
    float* hseq  = ws + 131072;        // [131072,196608)  dead after k_rnn_out
    float* uo    = ws + 196608;        // [196608,262144)  used by k_batch
    float* wp    = ws;                 // repacked weights alias pre_i AFTER k_rnn_out

    int Bv = in_sizes[0];              // 262144

    hipLaunchKernelGGL(k_rnn_pre, dim3(256), dim3(256), 0, stream,
                       u, i2h_w, i2h_b, h2o_w, h2o_b, pre_i, pre_o);
    hipLaunchKernelGGL(k_rnn_chain, dim3(1), dim3(256), 0, stream,
                       i2h_w, pre_i, hseq);
    hipLaunchKernelGGL(k_rnn_out, dim3(T_SEQ), dim3(64), 0, stream,
                       h2o_w, pre_o, hseq, uo);
    hipLaunchKernelGGL(k_repack, dim3(56), dim3(256), 0, stream,
                       xw1, uw1, xw2, uw2, xw3, uw3, cw, wp);
    hipLaunchKernelGGL(k_batch, dim3(Bv / 256), dim3(256), 0, stream,
                       t, x, uo, wp,
                       xb1, xb2, xb3, ub1, ub2, ub3, cb, out);
}